// Round 7
// baseline (208.243 us; speedup 1.0000x reference)
//
#include <hip/hip_runtime.h>
#include <hip/hip_bf16.h>

#define B_   2
#define N_   2048
#define DIM_ 1024
#define H_   16
#define DH_  64
#define SCALE_ 0.03125f  // DIM^-0.5 = 1/32

using bf16 = __hip_bfloat16;
typedef __bf16 bf16x8 __attribute__((ext_vector_type(8)));
typedef float  f32x4  __attribute__((ext_vector_type(4)));

__device__ __forceinline__ void gload16(const void* g, void* l) {
  __builtin_amdgcn_global_load_lds((const __attribute__((address_space(1))) void*)g,
                                   (__attribute__((address_space(3))) void*)l, 16, 0, 0);
}

// ---------------- fused prologue ----------------
__global__ __launch_bounds__(256) void prep_k(
    const float* __restrict__ x, const float* __restrict__ Wq,
    const float* __restrict__ Wkv, const float* __restrict__ Wo,
    bf16* __restrict__ xb, bf16* __restrict__ wqt,
    bf16* __restrict__ wkvt, bf16* __restrict__ wot) {
  __shared__ float tile[32][33];
  const int blk = blockIdx.x;
  if (blk < 4096) {
    const float* in; bf16* out; int C, bx, by;
    if (blk < 1024)      { in = Wq;  out = wqt;  C = 1024; bx = blk & 31; by = blk >> 5; }
    else if (blk < 3072) { int l = blk - 1024; in = Wkv; out = wkvt; C = 2048; bx = l & 63; by = l >> 6; }
    else                 { int l = blk - 3072; in = Wo;  out = wot;  C = 1024; bx = l & 31; by = l >> 5; }
    const int R = 1024;
    int tx = threadIdx.x & 31, ty = threadIdx.x >> 5;
    int r0 = by * 32, c0 = bx * 32;
#pragma unroll
    for (int i = 0; i < 32; i += 8)
      tile[ty + i][tx] = in[(size_t)(r0 + ty + i) * C + c0 + tx];
    __syncthreads();
#pragma unroll
    for (int i = 0; i < 32; i += 8)
      out[(size_t)(c0 + ty + i) * R + r0 + tx] = __float2bfloat16(tile[tx][ty + i]);
  } else {
    int i = (blk - 4096) * 256 + threadIdx.x;
    float4 v = ((const float4*)x)[i];
    bf16 t[4] = {__float2bfloat16(v.x), __float2bfloat16(v.y),
                 __float2bfloat16(v.z), __float2bfloat16(v.w)};
    ((ushort4*)xb)[i] = *(ushort4*)t;
  }
}

// ---------------- GEMM: C[M,Ncols] = A[M,K] @ Bt[Ncols,K]^T ----------------
// 2-phase double-buffered, BK=64.  LDS chunk-group c = 32 rows x 64 elem =
// 2048 ELEMENTS (bf16* arithmetic — the round-6 NaN was c*4096 here, an
// elements-vs-bytes OOB that corrupted the partner buffer).
// Swizzle: LDS[row][cb] holds global chunk cb^(row&7); read with same key.
template <int EPI>
__global__ __launch_bounds__(256) void gemm_bt_k(
    const bf16* __restrict__ A, const bf16* __restrict__ Bt,
    int M, int Ncols, int K,
    bf16* __restrict__ qb, bf16* __restrict__ kb, bf16* __restrict__ vt,
    float* __restrict__ Cout, const float* __restrict__ bias) {
  __shared__ bf16 As[2][128 * 64];
  __shared__ bf16 Bs[2][128 * 64];
  const int tid = threadIdx.x, lane = tid & 63, wid = tid >> 6;
  const int wr = wid >> 1, wc = wid & 1;
  const int m0 = blockIdx.y * 128, n0 = blockIdx.x * 128;
  const int l16 = lane & 15, lhi = lane >> 4;

  // staging: row c*32 + tid>>3, LDS chunk tid&7; source chunk inverse-swizzled
  const int srow = tid >> 3;
  const int sgc = ((tid & 7) ^ (srow & 7)) * 8;

#define GSTAGE(buf, kt)                                                              \
  {                                                                                  \
    _Pragma("unroll") for (int c = 0; c < 4; ++c) {                                  \
      int r = c * 32 + srow;                                                         \
      gload16(A + (size_t)(m0 + r) * K + (kt) * 64 + sgc,                            \
              (void*)(As[buf] + c * 2048 + tid * 8));                                \
      gload16(Bt + (size_t)(n0 + r) * K + (kt) * 64 + sgc,                           \
              (void*)(Bs[buf] + c * 2048 + tid * 8));                                \
    }                                                                                \
  }

  f32x4 acc[4][4] = {};
  const int nk = K >> 6;

  GSTAGE(0, 0);
  __syncthreads();

  for (int kt = 0; kt < nk; ++kt) {
    const int cur = kt & 1;
    if (kt + 1 < nk) GSTAGE(cur ^ 1, kt + 1);

    bf16x8 af[2][4], bfr[2][4];
#pragma unroll
    for (int ks = 0; ks < 2; ++ks) {
#pragma unroll
      for (int m = 0; m < 4; ++m)
        af[ks][m] = *(const bf16x8*)(As[cur] + (wr * 64 + m * 16 + l16) * 64 +
                                     (((ks * 4 + lhi) ^ (l16 & 7)) * 8));
#pragma unroll
      for (int n = 0; n < 4; ++n)
        bfr[ks][n] = *(const bf16x8*)(Bs[cur] + (wc * 64 + n * 16 + l16) * 64 +
                                      (((ks * 4 + lhi) ^ (l16 & 7)) * 8));
    }
#pragma unroll
    for (int ks = 0; ks < 2; ++ks)
#pragma unroll
      for (int m = 0; m < 4; ++m)
#pragma unroll
        for (int n = 0; n < 4; ++n)
          acc[m][n] =
              __builtin_amdgcn_mfma_f32_16x16x32_bf16(af[ks][m], bfr[ks][n], acc[m][n], 0, 0, 0);
    __syncthreads();
  }
#undef GSTAGE

#pragma unroll
  for (int m = 0; m < 4; ++m) {
    const int row = m0 + wr * 64 + m * 16 + lhi * 4;
#pragma unroll
    for (int n = 0; n < 4; ++n) {
      const int col = n0 + wc * 64 + n * 16 + l16;
#pragma unroll
      for (int r = 0; r < 4; ++r) {
        float v = acc[m][n][r];
        int rr = row + r;
        if (EPI == 0) {
          int b = rr >> 11, np = rr & (N_ - 1);
          if (col < DIM_) {
            int h = col >> 6, dh = col & 63;
            qb[(((size_t)b * H_ + h) * N_ + np) * DH_ + dh] = __float2bfloat16(v * SCALE_);
          } else if (col < 2 * DIM_) {
            int c2 = col - DIM_, h = c2 >> 6, dh = c2 & 63;
            kb[(((size_t)b * H_ + h) * N_ + np) * DH_ + dh] = __float2bfloat16(v);
          } else {
            int c2 = col - 2 * DIM_, h = c2 >> 6, dh = c2 & 63;
            vt[(((size_t)b * H_ + h) * DH_ + dh) * N_ + np] = __float2bfloat16(v);
          }
        } else {
          Cout[(size_t)rr * Ncols + col] = v + bias[col];
        }
      }
    }
  }
}

// ---------------- flash attention (v2 + defer-max T13) ----------------
__global__ __launch_bounds__(256, 4) void attn_k(const bf16* __restrict__ qb,
                                                 const bf16* __restrict__ kb,
                                                 const bf16* __restrict__ vt,
                                                 bf16* __restrict__ ob) {
  __shared__ bf16 KV[2][2][4096];  // [buf][K=0/V=1][64 rows x 64 cols]
  __shared__ bf16 P[4][1024];      // per-wave 16 x 64 P tile
  const int tid = threadIdx.x, lane = tid & 63, w = tid >> 6;
  const int l16 = lane & 15, lhi = lane >> 4;
  const int bh = blockIdx.x & 31, b = bh >> 4, h = bh & 15;
  const int qt = 31 - (blockIdx.x >> 5);
  const int q0 = qt * 64 + w * 16;
  const int swz = (l16 & 7) << 4;

  const int srow = tid >> 3;
  const int ssc = ((tid & 7) * 16) ^ ((srow & 7) << 4);
  const char* kbase = (const char*)kb + ((size_t)bh * N_) * 128;
  const char* vbase = (const char*)vt + ((size_t)bh * DH_) * 4096;

#define STAGE(buf, j0s)                                                          \
  {                                                                              \
    _Pragma("unroll") for (int c = 0; c < 2; ++c) {                              \
      int ro = c * 32 + srow;                                                    \
      gload16(kbase + (size_t)((j0s) + ro) * 128 + ssc,                          \
              (char*)&KV[buf][0][0] + c * 4096 + tid * 16);                      \
      gload16(vbase + (size_t)ro * 4096 + (j0s) * 2 + ssc,                       \
              (char*)&KV[buf][1][0] + c * 4096 + tid * 16);                      \
    }                                                                            \
  }

  const bf16* qp = qb + ((size_t)bh * N_ + q0 + l16) * DH_ + lhi * 8;
  bf16x8 qa0 = *(const bf16x8*)qp;
  bf16x8 qa1 = *(const bf16x8*)(qp + 32);

  f32x4 o[4] = {};
  float mr = -1e30f, lr = 0.f;
  char* Pw = (char*)&P[w][0];

  STAGE(0, 0);
  __syncthreads();

  for (int jt = 0; jt <= qt; ++jt) {
    const int cur = jt & 1;
    if (jt < qt) STAGE(cur ^ 1, (jt + 1) * 64);

    const char* Kb = (const char*)&KV[cur][0][0];
    const char* Vb = (const char*)&KV[cur][1][0];
    const bool diag = (jt == qt);
    const int jnmax = diag ? (w + 1) : 4;

    f32x4 s[4];
#pragma unroll
    for (int jn = 0; jn < 4; ++jn) {
      if (jn < jnmax) {
        const char* kr = Kb + (jn * 16 + l16) * 128;
        bf16x8 k0 = *(const bf16x8*)(kr + ((lhi * 16) ^ swz));
        bf16x8 k1 = *(const bf16x8*)(kr + ((64 + lhi * 16) ^ swz));
        f32x4 t = {};
        t = __builtin_amdgcn_mfma_f32_16x16x32_bf16(k0, qa0, t, 0, 0, 0);
        t = __builtin_amdgcn_mfma_f32_16x16x32_bf16(k1, qa1, t, 0, 0, 0);
        s[jn] = t;
      } else {
        s[jn] = f32x4{-1e30f, -1e30f, -1e30f, -1e30f};
      }
    }
    if (diag) {
#pragma unroll
      for (int jn = 0; jn < 4; ++jn)
#pragma unroll
        for (int r = 0; r < 4; ++r)
          if (jn * 16 + lhi * 4 + r > w * 16 + l16) s[jn][r] = -1e30f;
    }

    float pm = s[0][0];
#pragma unroll
    for (int jn = 0; jn < 4; ++jn)
#pragma unroll
      for (int r = 0; r < 4; ++r) pm = fmaxf(pm, s[jn][r]);
    pm = fmaxf(pm, __shfl_xor(pm, 16, 64));
    pm = fmaxf(pm, __shfl_xor(pm, 32, 64));

    // defer-max (T13): if max grew by <= 8, keep old mr -> skip O-rescale.
    // P bounded by e^8 ~ 2981; f32 accum tolerates. First iter mr=-1e30 ->
    // never defers.  __all is wave-uniform -> no divergence.
    const bool defer = __all(pm - mr <= 8.0f);
    if (!defer) {
      float mn = fmaxf(mr, pm);
      float fac = __expf(mr - mn);
      mr = mn;
      lr *= fac;
      float fr[4];
#pragma unroll
      for (int r = 0; r < 4; ++r) fr[r] = __shfl(fac, lhi * 4 + r, 64);
#pragma unroll
      for (int dn = 0; dn < 4; ++dn)
#pragma unroll
        for (int r = 0; r < 4; ++r) o[dn][r] *= fr[r];
    }

    float rs = 0.f;
#pragma unroll
    for (int jn = 0; jn < 4; ++jn) {
      bf16 pk[4];
#pragma unroll
      for (int r = 0; r < 4; ++r) {
        float p = __expf(s[jn][r] - mr);
        rs += p;
        pk[r] = __float2bfloat16(p);
      }
      *(short4*)(Pw + l16 * 128 + ((jn * 32 + lhi * 8) ^ swz)) = *(short4*)pk;
    }
    rs += __shfl_xor(rs, 16, 64);
    rs += __shfl_xor(rs, 32, 64);
    lr += rs;

    bf16x8 pa0 = *(const bf16x8*)(Pw + l16 * 128 + ((lhi * 16) ^ swz));
    bf16x8 pa1 = *(const bf16x8*)(Pw + l16 * 128 + ((64 + lhi * 16) ^ swz));

#pragma unroll
    for (int dn = 0; dn < 4; ++dn) {
      const char* vr = Vb + (dn * 16 + l16) * 128;
      bf16x8 v0 = *(const bf16x8*)(vr + ((lhi * 16) ^ swz));
      bf16x8 v1 = *(const bf16x8*)(vr + ((64 + lhi * 16) ^ swz));
      o[dn] = __builtin_amdgcn_mfma_f32_16x16x32_bf16(pa0, v0, o[dn], 0, 0, 0);
      o[dn] = __builtin_amdgcn_mfma_f32_16x16x32_bf16(pa1, v1, o[dn], 0, 0, 0);
    }
    __syncthreads();
  }

  float lf[4];
#pragma unroll
  for (int r = 0; r < 4; ++r) lf[r] = __shfl(lr, lhi * 4 + r, 64);
#pragma unroll
  for (int dn = 0; dn < 4; ++dn)
#pragma unroll
    for (int r = 0; r < 4; ++r) {
      int nrow = q0 + lhi * 4 + r;
      float v = o[dn][r] / lf[r];
      ob[((size_t)b * N_ + nrow) * DIM_ + h * DH_ + dn * 16 + l16] = __float2bfloat16(v);
    }
#undef STAGE
}

// ---------------- launcher ----------------
extern "C" void kernel_launch(void* const* d_in, const int* in_sizes, int n_in,
                              void* d_out, int out_size, void* d_ws, size_t ws_size,
                              hipStream_t stream) {
  const float* x   = (const float*)d_in[0];
  const float* Wq  = (const float*)d_in[2];
  const float* Wkv = (const float*)d_in[3];
  const float* Wo  = (const float*)d_in[4];
  const float* bo  = (const float*)d_in[5];
  float* out = (float*)d_out;
  char* ws = (char*)d_ws;
  const size_t MB = 1u << 20;
  bf16* xb   = (bf16*)(ws + 0 * MB);
  bf16* qb   = (bf16*)(ws + 8 * MB);
  bf16* kb   = (bf16*)(ws + 16 * MB);
  bf16* vt   = (bf16*)(ws + 24 * MB);
  bf16* ab   = (bf16*)(ws + 32 * MB);
  bf16* wqt  = (bf16*)(ws + 40 * MB);
  bf16* wkvt = (bf16*)(ws + 42 * MB);
  bf16* wot  = (bf16*)(ws + 46 * MB);

  prep_k<<<dim3(8192), dim3(256), 0, stream>>>(x, Wq, Wkv, Wo, xb, wqt, wkvt, wot);

  gemm_bt_k<0><<<dim3(24, 32), dim3(256), 0, stream>>>(
      xb, wqt, B_ * N_, 3 * DIM_, DIM_, qb, kb, vt, nullptr, nullptr);
  attn_k<<<dim3(1024), dim3(256), 0, stream>>>(qb, kb, vt, ab);
  gemm_bt_k<1><<<dim3(8, 32), dim3(256), 0, stream>>>(
      ab, wot, B_ * N_, DIM_, DIM_, nullptr, nullptr, nullptr, out, bo);
}

// Round 14
// 196.447 us; speedup vs baseline: 1.0600x; 1.0600x over previous
//
#include <hip/hip_runtime.h>
#include <hip/hip_bf16.h>

#define B_   2
#define N_   2048
#define DIM_ 1024
#define H_   16
#define DH_  64
#define SCALE_ 0.03125f  // DIM^-0.5 = 1/32

using bf16 = __hip_bfloat16;
typedef __bf16 bf16x8 __attribute__((ext_vector_type(8)));
typedef float  f32x4  __attribute__((ext_vector_type(4)));

__device__ __forceinline__ void gload16(const void* g, void* l) {
  __builtin_amdgcn_global_load_lds((const __attribute__((address_space(1))) void*)g,
                                   (__attribute__((address_space(3))) void*)l, 16, 0, 0);
}

// ---------------- fused prologue ----------------
__global__ __launch_bounds__(256) void prep_k(
    const float* __restrict__ x, const float* __restrict__ Wq,
    const float* __restrict__ Wkv, const float* __restrict__ Wo,
    bf16* __restrict__ xb, bf16* __restrict__ wqt,
    bf16* __restrict__ wkvt, bf16* __restrict__ wot) {
  __shared__ float tile[32][33];
  const int blk = blockIdx.x;
  if (blk < 4096) {
    const float* in; bf16* out; int C, bx, by;
    if (blk < 1024)      { in = Wq;  out = wqt;  C = 1024; bx = blk & 31; by = blk >> 5; }
    else if (blk < 3072) { int l = blk - 1024; in = Wkv; out = wkvt; C = 2048; bx = l & 63; by = l >> 6; }
    else                 { int l = blk - 3072; in = Wo;  out = wot;  C = 1024; bx = l & 31; by = l >> 5; }
    const int R = 1024;
    int tx = threadIdx.x & 31, ty = threadIdx.x >> 5;
    int r0 = by * 32, c0 = bx * 32;
#pragma unroll
    for (int i = 0; i < 32; i += 8)
      tile[ty + i][tx] = in[(size_t)(r0 + ty + i) * C + c0 + tx];
    __syncthreads();
#pragma unroll
    for (int i = 0; i < 32; i += 8)
      out[(size_t)(c0 + ty + i) * R + r0 + tx] = __float2bfloat16(tile[tx][ty + i]);
  } else {
    int i = (blk - 4096) * 256 + threadIdx.x;
    float4 v = ((const float4*)x)[i];
    bf16 t[4] = {__float2bfloat16(v.x), __float2bfloat16(v.y),
                 __float2bfloat16(v.z), __float2bfloat16(v.w)};
    ((ushort4*)xb)[i] = *(ushort4*)t;
  }
}

// ---------------- GEMM: C[M,Ncols] = A[M,K] @ Bt[Ncols,K]^T ----------------
// BK=32, 2-phase double-buffered (round-5 measured best: 46.5us/555TF QKV).
// BK=64 regressed to 80us (m132-style occupancy loss: 64KB LDS capped
// co-residency 3->2 blocks/CU and exposed the barrier drains) — do not redo.
template <int EPI>
__global__ __launch_bounds__(256) void gemm_bt_k(
    const bf16* __restrict__ A, const bf16* __restrict__ Bt,
    int M, int Ncols, int K,
    bf16* __restrict__ qb, bf16* __restrict__ kb, bf16* __restrict__ vt,
    float* __restrict__ Cout, const float* __restrict__ bias) {
  __shared__ bf16 As[2][128 * 32];
  __shared__ bf16 Bs[2][128 * 32];
  const int tid = threadIdx.x, lane = tid & 63, wid = tid >> 6;
  const int wr = wid >> 1, wc = wid & 1;
  const int m0 = blockIdx.y * 128, n0 = blockIdx.x * 128;
  const int l16 = lane & 15, lhi = lane >> 4;

  const int srow = lane >> 2;
  const int sblk = (lane & 3) ^ ((lane >> 3) & 3);
  const int rblk = lhi ^ ((l16 >> 1) & 3);

#define GSTAGE(buf, kt)                                                              \
  {                                                                                  \
    _Pragma("unroll") for (int c = 0; c < 2; ++c) {                                  \
      int ch = wid * 2 + c;                                                          \
      int row = ch * 16 + srow;                                                      \
      gload16(A + (size_t)(m0 + row) * K + (kt) + sblk * 8,                          \
              (void*)(As[buf] + ch * 512 + lane * 8));                               \
      gload16(Bt + (size_t)(n0 + row) * K + (kt) + sblk * 8,                         \
              (void*)(Bs[buf] + ch * 512 + lane * 8));                               \
    }                                                                                \
  }

  f32x4 acc[4][4] = {};
  const int nk = K >> 5;

  GSTAGE(0, 0);
  __syncthreads();

  for (int kt = 0; kt < nk; ++kt) {
    const int cur = kt & 1;
    if (kt + 1 < nk) GSTAGE(cur ^ 1, (kt + 1) * 32);

    bf16x8 af[4], bfr[4];
#pragma unroll
    for (int m = 0; m < 4; ++m)
      af[m] = *(const bf16x8*)(As[cur] + (wr * 64 + m * 16 + l16) * 32 + rblk * 8);
#pragma unroll
    for (int n = 0; n < 4; ++n)
      bfr[n] = *(const bf16x8*)(Bs[cur] + (wc * 64 + n * 16 + l16) * 32 + rblk * 8);
#pragma unroll
    for (int m = 0; m < 4; ++m)
#pragma unroll
      for (int n = 0; n < 4; ++n)
        acc[m][n] = __builtin_amdgcn_mfma_f32_16x16x32_bf16(af[m], bfr[n], acc[m][n], 0, 0, 0);
    __syncthreads();
  }
#undef GSTAGE

#pragma unroll
  for (int m = 0; m < 4; ++m) {
    const int row = m0 + wr * 64 + m * 16 + lhi * 4;
#pragma unroll
    for (int n = 0; n < 4; ++n) {
      const int col = n0 + wc * 64 + n * 16 + l16;
#pragma unroll
      for (int r = 0; r < 4; ++r) {
        float v = acc[m][n][r];
        int rr = row + r;
        if (EPI == 0) {
          int b = rr >> 11, np = rr & (N_ - 1);
          if (col < DIM_) {
            int h = col >> 6, dh = col & 63;
            qb[(((size_t)b * H_ + h) * N_ + np) * DH_ + dh] = __float2bfloat16(v * SCALE_);
          } else if (col < 2 * DIM_) {
            int c2 = col - DIM_, h = c2 >> 6, dh = c2 & 63;
            kb[(((size_t)b * H_ + h) * N_ + np) * DH_ + dh] = __float2bfloat16(v);
          } else {
            int c2 = col - 2 * DIM_, h = c2 >> 6, dh = c2 & 63;
            vt[(((size_t)b * H_ + h) * DH_ + dh) * N_ + np] = __float2bfloat16(v);
          }
        } else {
          Cout[(size_t)rr * Ncols + col] = v + bias[col];
        }
      }
    }
  }
}

// ---------------- flash attention (v2 + defer-max T13) ----------------
__global__ __launch_bounds__(256, 4) void attn_k(const bf16* __restrict__ qb,
                                                 const bf16* __restrict__ kb,
                                                 const bf16* __restrict__ vt,
                                                 bf16* __restrict__ ob) {
  __shared__ bf16 KV[2][2][4096];  // [buf][K=0/V=1][64 rows x 64 cols]
  __shared__ bf16 P[4][1024];      // per-wave 16 x 64 P tile
  const int tid = threadIdx.x, lane = tid & 63, w = tid >> 6;
  const int l16 = lane & 15, lhi = lane >> 4;
  const int bh = blockIdx.x & 31, b = bh >> 4, h = bh & 15;
  const int qt = 31 - (blockIdx.x >> 5);
  const int q0 = qt * 64 + w * 16;
  const int swz = (l16 & 7) << 4;

  const int srow = tid >> 3;
  const int ssc = ((tid & 7) * 16) ^ ((srow & 7) << 4);
  const char* kbase = (const char*)kb + ((size_t)bh * N_) * 128;
  const char* vbase = (const char*)vt + ((size_t)bh * DH_) * 4096;

#define STAGE(buf, j0s)                                                          \
  {                                                                              \
    _Pragma("unroll") for (int c = 0; c < 2; ++c) {                              \
      int ro = c * 32 + srow;                                                    \
      gload16(kbase + (size_t)((j0s) + ro) * 128 + ssc,                          \
              (char*)&KV[buf][0][0] + c * 4096 + tid * 16);                      \
      gload16(vbase + (size_t)ro * 4096 + (j0s) * 2 + ssc,                       \
              (char*)&KV[buf][1][0] + c * 4096 + tid * 16);                      \
    }                                                                            \
  }

  const bf16* qp = qb + ((size_t)bh * N_ + q0 + l16) * DH_ + lhi * 8;
  bf16x8 qa0 = *(const bf16x8*)qp;
  bf16x8 qa1 = *(const bf16x8*)(qp + 32);

  f32x4 o[4] = {};
  float mr = -1e30f, lr = 0.f;
  char* Pw = (char*)&P[w][0];

  STAGE(0, 0);
  __syncthreads();

  for (int jt = 0; jt <= qt; ++jt) {
    const int cur = jt & 1;
    if (jt < qt) STAGE(cur ^ 1, (jt + 1) * 64);

    const char* Kb = (const char*)&KV[cur][0][0];
    const char* Vb = (const char*)&KV[cur][1][0];
    const bool diag = (jt == qt);
    const int jnmax = diag ? (w + 1) : 4;

    f32x4 s[4];
#pragma unroll
    for (int jn = 0; jn < 4; ++jn) {
      if (jn < jnmax) {
        const char* kr = Kb + (jn * 16 + l16) * 128;
        bf16x8 k0 = *(const bf16x8*)(kr + ((lhi * 16) ^ swz));
        bf16x8 k1 = *(const bf16x8*)(kr + ((64 + lhi * 16) ^ swz));
        f32x4 t = {};
        t = __builtin_amdgcn_mfma_f32_16x16x32_bf16(k0, qa0, t, 0, 0, 0);
        t = __builtin_amdgcn_mfma_f32_16x16x32_bf16(k1, qa1, t, 0, 0, 0);
        s[jn] = t;
      } else {
        s[jn] = f32x4{-1e30f, -1e30f, -1e30f, -1e30f};
      }
    }
    if (diag) {
#pragma unroll
      for (int jn = 0; jn < 4; ++jn)
#pragma unroll
        for (int r = 0; r < 4; ++r)
          if (jn * 16 + lhi * 4 + r > w * 16 + l16) s[jn][r] = -1e30f;
    }

    float pm = s[0][0];
#pragma unroll
    for (int jn = 0; jn < 4; ++jn)
#pragma unroll
      for (int r = 0; r < 4; ++r) pm = fmaxf(pm, s[jn][r]);
    pm = fmaxf(pm, __shfl_xor(pm, 16, 64));
    pm = fmaxf(pm, __shfl_xor(pm, 32, 64));

    // defer-max (T13): if max grew by <= 8, keep old mr -> skip O-rescale.
    const bool defer = __all(pm - mr <= 8.0f);
    if (!defer) {
      float mn = fmaxf(mr, pm);
      float fac = __expf(mr - mn);
      mr = mn;
      lr *= fac;
      float fr[4];
#pragma unroll
      for (int r = 0; r < 4; ++r) fr[r] = __shfl(fac, lhi * 4 + r, 64);
#pragma unroll
      for (int dn = 0; dn < 4; ++dn)
#pragma unroll
        for (int r = 0; r < 4; ++r) o[dn][r] *= fr[r];
    }

    float rs = 0.f;
#pragma unroll
    for (int jn = 0; jn < 4; ++jn) {
      bf16 pk[4];
#pragma unroll
      for (int r = 0; r < 4; ++r) {
        float p = __expf(s[jn][r] - mr);
        rs += p;
        pk[r] = __float2bfloat16(p);
      }
      *(short4*)(Pw + l16 * 128 + ((jn * 32 + lhi * 8) ^ swz)) = *(short4*)pk;
    }
    rs += __shfl_xor(rs, 16, 64);
    rs += __shfl_xor(rs, 32, 64);
    lr += rs;

    bf16x8 pa0 = *(const bf16x8*)(Pw + l16 * 128 + ((lhi * 16) ^ swz));
    bf16x8 pa1 = *(const bf16x8*)(Pw + l16 * 128 + ((64 + lhi * 16) ^ swz));

#pragma unroll
    for (int dn = 0; dn < 4; ++dn) {
      const char* vr = Vb + (dn * 16 + l16) * 128;
      bf16x8 v0 = *(const bf16x8*)(vr + ((lhi * 16) ^ swz));
      bf16x8 v1 = *(const bf16x8*)(vr + ((64 + lhi * 16) ^ swz));
      o[dn] = __builtin_amdgcn_mfma_f32_16x16x32_bf16(pa0, v0, o[dn], 0, 0, 0);
      o[dn] = __builtin_amdgcn_mfma_f32_16x16x32_bf16(pa1, v1, o[dn], 0, 0, 0);
    }
    __syncthreads();
  }

  float lf[4];
#pragma unroll
  for (int r = 0; r < 4; ++r) lf[r] = __shfl(lr, lhi * 4 + r, 64);
#pragma unroll
  for (int dn = 0; dn < 4; ++dn)
#pragma unroll
    for (int r = 0; r < 4; ++r) {
      int nrow = q0 + lhi * 4 + r;
      float v = o[dn][r] / lf[r];
      ob[((size_t)b * N_ + nrow) * DIM_ + h * DH_ + dn * 16 + l16] = __float2bfloat16(v);
    }
#undef STAGE
}

// ---------------- launcher ----------------
extern "C" void kernel_launch(void* const* d_in, const int* in_sizes, int n_in,
                              void* d_out, int out_size, void* d_ws, size_t ws_size,
                              hipStream_t stream) {
  const float* x   = (const float*)d_in[0];
  const float* Wq  = (const float*)d_in[2];
  const float* Wkv = (const float*)d_in[3];
  const float* Wo  = (const float*)d_in[4];
  const float* bo  = (const float*)d_in[5];
  float* out = (float*)d_out;
  char* ws = (char*)d_ws;
  const size_t MB = 1u << 20;
  bf16* xb   = (bf16*)(ws + 0 * MB);
  bf16* qb   = (bf16*)(ws + 8 * MB);
  bf16* kb   = (bf16*)(ws + 16 * MB);
  bf16* vt   = (bf16*)(ws + 24 * MB);
  bf16* ab   = (bf16*)(ws + 32 * MB);
  bf16* wqt  = (bf16*)(ws + 40 * MB);
  bf16* wkvt = (bf16*)(ws + 42 * MB);
  bf16* wot  = (bf16*)(ws + 46 * MB);

  prep_k<<<dim3(8192), dim3(256), 0, stream>>>(x, Wq, Wkv, Wo, xb, wqt, wkvt, wot);

  gemm_bt_k<0><<<dim3(24, 32), dim3(256), 0, stream>>>(
      xb, wqt, B_ * N_, 3 * DIM_, DIM_, qb, kb, vt, nullptr, nullptr);
  attn_k<<<dim3(1024), dim3(256), 0, stream>>>(qb, kb, vt, ab);
  gemm_bt_k<1><<<dim3(8, 32), dim3(256), 0, stream>>>(
      ab, wot, B_ * N_, DIM_, DIM_, nullptr, nullptr, nullptr, out, bo);
}